// Round 5
// baseline (464.747 us; speedup 1.0000x reference)
//
#include <hip/hip_runtime.h>
#include <math.h>

// Problem constants
#define CC 3
#define HH 1280
#define WW 720
#define BSZ 20
#define NHB 64
#define NWB 36
#define NBLK (NHB*NWB)          // 2304
#define OUT_IMG (3*5120*2880)   // 44236800

// Union'd LDS: light and gate are block-uniform branches of one kernel.
union __align__(16) SMem {
  struct {
    float in_s[3][22][28];      // zero-padded input block; pitch 28 (rows 16B-aligned)
    float w_t[27][48];          // transposed weights: [k=(ic*3+ky)*3+kx][oc]
    float b_s[48];
  } L;                           // ~12.8 KB
  struct {
    float ins[3][26][28];       // clamped input patch (edge pad baked in)
    float w1s[16*27];           // conv1 weights, natural layout (1-oc stage A)
    float b1s[16];
    float w2s[8*16*9];
    float b2s[8];
    float w3s[200];
    float x1s[16][12][14];      // post-pool conv1 patch, cols padded to 14 (8B-aligned float2)
    float red[256];
    float b3s;
  } G;                           // ~27.8 KB
};

__device__ __forceinline__ float fast_tanh(float x) {
  const float ax = fabsf(x);
  const float e = __expf(-2.0f * ax);
  const float t = (1.0f - e) / (1.0f + e);
  return x < 0.0f ? -t : t;
}

// ---------------------------------------------------------------------------
// One half-row (10 output cols) of the light conv for a 4-oc pixel-shuffle
// quad. HALF is a template parameter: every register-array index is
// compile-time (rule: runtime-indexed arrays go to scratch).
// Live set ~85 VGPR: acc[4][10]=40 + r[16] + 3 weight float4s + addressing.
// ---------------------------------------------------------------------------
template<int HALF>
__device__ __forceinline__ void light_pass(
    SMem& sm, int h, int ocg, float* __restrict__ orow) {
  float acc[4][10];
  {
    const float4 b4 = *(const float4*)&sm.L.b_s[4*ocg];
    #pragma unroll
    for (int u = 0; u < 10; ++u) {
      acc[0][u] = b4.x; acc[1][u] = b4.y; acc[2][u] = b4.z; acc[3][u] = b4.w;
    }
  }

  #pragma unroll
  for (int ic = 0; ic < 3; ++ic)
    #pragma unroll
    for (int ky = 0; ky < 3; ++ky) {
      // 16 input cols starting at 8*HALF (32B offset -> still 16B-aligned).
      // Output col w = 10*HALF+u needs local index 2*HALF+u+kx (compile-time).
      const float* row = &sm.L.in_s[ic][h + ky][8*HALF];
      float r[16];
      #pragma unroll
      for (int j = 0; j < 4; ++j) {
        float4 v = ((const float4*)row)[j];          // ds_read_b128, ~6 addrs/wave
        r[4*j+0] = v.x; r[4*j+1] = v.y; r[4*j+2] = v.z; r[4*j+3] = v.w;
      }
      const int kbase = (ic*3 + ky)*3;
      const float4 wv0 = *(const float4*)&sm.L.w_t[kbase + 0][4*ocg];
      const float4 wv1 = *(const float4*)&sm.L.w_t[kbase + 1][4*ocg];
      const float4 wv2 = *(const float4*)&sm.L.w_t[kbase + 2][4*ocg];
      #pragma unroll
      for (int u = 0; u < 10; ++u) {
        const float x0 = r[2*HALF + u + 0];
        const float x1 = r[2*HALF + u + 1];
        const float x2 = r[2*HALF + u + 2];
        acc[0][u] += x0*wv0.x + x1*wv1.x + x2*wv2.x;
        acc[1][u] += x0*wv0.y + x1*wv1.y + x2*wv2.y;
        acc[2][u] += x0*wv0.z + x1*wv1.z + x2*wv2.z;
        acc[3][u] += x0*wv0.w + x1*wv1.w + x2*wv2.w;
      }
    }

  // store: cols [40*HALF, 40*HALF+40) of the output row; q = float4 lane (=r2)
  #pragma unroll
  for (int u = 0; u < 10; ++u) {
    float4 v;
    v.x = fminf(fmaxf(acc[0][u], 0.0f), 0.6f) + 0.4f;
    v.y = fminf(fmaxf(acc[1][u], 0.0f), 0.6f) + 0.4f;
    v.z = fminf(fmaxf(acc[2][u], 0.0f), 0.6f) + 0.4f;
    v.w = fminf(fmaxf(acc[3][u], 0.0f), 0.6f) + 0.4f;
    *(float4*)&orow[40*HALF + 4*u] = v;
  }
}

// ---------------------------------------------------------------------------
// Light expert: per 20x20 block, zero-pad conv3x3 (3->48) + pixel_shuffle(4)
// + clamp[0,0.6]+0.4. mask always False -> complex expert dead.
// Thread = (h, ocg): 4 output channels (one pixel-shuffle quad) x 20 cols,
// two sequential 10-col template passes with a sched_barrier between them so
// the scheduler cannot merge their live ranges (round-4: merged -> 152 VGPR
// -> 3 waves/SIMD -> latency-bound at 256us).
// ---------------------------------------------------------------------------
__device__ __forceinline__ void light_body(
    SMem& sm, int l,
    const float* __restrict__ inp,
    const float* __restrict__ wl,
    const float* __restrict__ bl,
    float* __restrict__ out) {
  const int bi = l / NWB, bj = l % NWB;
  const int tid = threadIdx.x;

  // transposed weight staging: w_t[k][oc] = wl[oc*27 + k]  (5KB, L2-hot)
  for (int i = tid; i < 27*48; i += 256) {
    int k = i / 48, oc = i - k*48;
    sm.L.w_t[k][oc] = wl[oc*27 + k];
  }
  if (tid < 48) sm.L.b_s[tid] = bl[tid];
  for (int i = tid; i < 3*22*28; i += 256) ((float*)sm.L.in_s)[i] = 0.0f;
  __syncthreads();
  // stage 20x20x3 block; global float4 loads (WW=720 and 20*bj are mult of 4)
  for (int i = tid; i < 300; i += 256) {
    int x4 = i % 5; int r = (i / 5) % 20; int c = i / 100;
    const float4 v = *(const float4*)&inp[(c*HH + bi*BSZ + r)*WW + bj*BSZ + 4*x4];
    float* dst = &sm.L.in_s[c][r+1][1 + 4*x4];
    dst[0] = v.x; dst[1] = v.y; dst[2] = v.z; dst[3] = v.w;
  }
  __syncthreads();

  if (tid < 240) {
    const int ocg = tid % 12;            // oc quad: oc = 4*ocg + q (q = f4 lane)
    const int h   = tid / 12;            // conv row 0..19
    const int c   = ocg >> 2;            // pixel-shuffle: c  = oc>>4
    const int r1  = ocg & 3;             //                r1 = (oc>>2)&3 ; r2 = q

    const int gy = bi*80 + 4*h + r1;
    float* orow = &out[(c*5120 + gy)*2880 + bj*80];
    light_pass<0>(sm, h, ocg, orow);
    __builtin_amdgcn_sched_barrier(0);   // no code motion across: register reuse
    light_pass<1>(sm, h, ocg, orow);
  }
}

// ---------------------------------------------------------------------------
// Fused gate CNN (stage A reverted to round-1 1-oc form: ~48 VGPR proven;
// the 4-oc variant was a register driver at 84-152 VGPR):
//   stage A: conv1(3->16, edge-pad) + tanh + maxpool2 on a local 12x12 patch
//   stage B: conv2(16->8, edge-pad) + maxpool2 -> 8x5x5 window
//   stage C: 5x5x8 dot (conv3 stride 5) + sigmoid -> 1 scalar
// ---------------------------------------------------------------------------
__device__ __forceinline__ void gate_body(
    SMem& sm, int l,
    const float* __restrict__ inp,
    const float* __restrict__ w1,
    const float* __restrict__ b1,
    const float* __restrict__ w2,
    const float* __restrict__ b2,
    const float* __restrict__ w3,
    const float* __restrict__ b3,
    float* __restrict__ cv) {
  const int tid = threadIdx.x;
  const int oy = l / NWB, ox = l % NWB;

  for (int i = tid; i < 16*27; i += 256) sm.G.w1s[i] = w1[i];
  for (int i = tid; i < 8*16*9; i += 256) sm.G.w2s[i] = w2[i];
  for (int i = tid; i < 200; i += 256) sm.G.w3s[i] = w3[i];
  if (tid < 16) sm.G.b1s[tid] = b1[tid];
  if (tid < 8)  sm.G.b2s[tid] = b2[tid];
  if (tid == 0) sm.G.b3s = b3[0];

  // input patch rows [20*oy-3, 20*oy+23), cols [20*ox-3, 20*ox+23), clamped
  for (int i = tid; i < 3*26*28; i += 256) {
    int b = i % 28; int a = (i / 28) % 26; int ic = i / (26*28);
    int gy = 20*oy - 3 + a; gy = gy < 0 ? 0 : (gy > HH-1 ? HH-1 : gy);
    int gx = 20*ox - 3 + b; gx = gx < 0 ? 0 : (gx > WW-1 ? WW-1 : gx);
    sm.G.ins[ic][a][b] = inp[(ic*HH + gy)*WW + gx];
  }
  __syncthreads();

  // ---- stage A: one oc per thread-iteration (round-1 form, low VGPR)
  for (int v = tid; v < 16*12*12; v += 256) {
    int oc = v / 144; int rem = v - oc*144; int ly = rem / 12; int lx = rem - ly*12;
    int y1 = 10*oy - 1 + ly; y1 = y1 < 0 ? 0 : (y1 > 639 ? 639 : y1);
    int x1 = 10*ox - 1 + lx; x1 = x1 < 0 ? 0 : (x1 > 359 ? 359 : x1);
    const int ry = 2*y1 + 2 - 20*oy;   // even, in [0,22]
    const int rx = 2*x1 + 2 - 20*ox;   // even, in [0,24]
    float patch[3][4][4];
    #pragma unroll
    for (int ic = 0; ic < 3; ++ic)
      #pragma unroll
      for (int d = 0; d < 4; ++d) {
        const float2 pa = *(const float2*)&sm.G.ins[ic][ry + d][rx];
        const float2 pb = *(const float2*)&sm.G.ins[ic][ry + d][rx + 2];
        patch[ic][d][0] = pa.x; patch[ic][d][1] = pa.y;
        patch[ic][d][2] = pb.x; patch[ic][d][3] = pb.y;
      }
    float m = -1e30f;
    #pragma unroll
    for (int sy = 0; sy < 2; ++sy)
      #pragma unroll
      for (int sx = 0; sx < 2; ++sx) {
        float acc = sm.G.b1s[oc];
        #pragma unroll
        for (int ic = 0; ic < 3; ++ic)
          #pragma unroll
          for (int ky = 0; ky < 3; ++ky)
            #pragma unroll
            for (int kx = 0; kx < 3; ++kx)
              acc += patch[ic][sy+ky][sx+kx] * sm.G.w1s[(oc*3+ic)*9 + ky*3 + kx];
        m = fmaxf(m, acc);
      }
    // tanh monotonic: maxpool(tanh(.)) == tanh(maxpool(.))
    sm.G.x1s[oc][ly][lx] = fast_tanh(m);
  }
  __syncthreads();

  // ---- stage B
  float prod = 0.0f;
  if (tid < 200) {
    int oc2 = tid / 25; int rem = tid - oc2*25; int j = rem / 5; int i5 = rem - j*5;
    float a00 = sm.G.b2s[oc2], a01 = a00, a10 = a00, a11 = a00;
    for (int ic = 0; ic < 16; ++ic) {
      float p[4][4];
      #pragma unroll
      for (int d = 0; d < 4; ++d) {
        const float2 pa = *(const float2*)&sm.G.x1s[ic][2*j + d][2*i5];
        const float2 pb = *(const float2*)&sm.G.x1s[ic][2*j + d][2*i5 + 2];
        p[d][0] = pa.x; p[d][1] = pa.y; p[d][2] = pb.x; p[d][3] = pb.y;
      }
      #pragma unroll
      for (int ky = 0; ky < 3; ++ky)
        #pragma unroll
        for (int kx = 0; kx < 3; ++kx) {
          float wv = sm.G.w2s[((oc2*16 + ic)*3 + ky)*3 + kx];
          a00 += p[ky  ][kx  ]*wv;
          a01 += p[ky  ][kx+1]*wv;
          a10 += p[ky+1][kx  ]*wv;
          a11 += p[ky+1][kx+1]*wv;
        }
    }
    float x2 = fmaxf(fmaxf(a00, a01), fmaxf(a10, a11));
    prod = x2 * sm.G.w3s[tid];          // w3 index (oc2*5+j)*5+i5 == tid
  }
  sm.G.red[tid] = prod;
  __syncthreads();

  // ---- stage C
  if (tid < 64) {
    float s = sm.G.red[tid] + sm.G.red[tid+64] + sm.G.red[tid+128] + sm.G.red[tid+192];
    #pragma unroll
    for (int off = 32; off > 0; off >>= 1) s += __shfl_down(s, off);
    if (tid == 0)
      cv[l] = 1.0f / (1.0f + expf(-(s + sm.G.b3s)));
  }
}

// ---------------------------------------------------------------------------
// One launch, interleaved light/gate blocks (block-uniform branch).
// __launch_bounds__(256,5): cap allocator at ~102 VGPR -> 5 waves/SIMD
// (20 waves/CU, the occupancy regime that made round-1 fast).
// ---------------------------------------------------------------------------
__global__ __launch_bounds__(256, 5) void fused_kernel(
    const float* __restrict__ inp,
    const float* __restrict__ w1,
    const float* __restrict__ b1,
    const float* __restrict__ w2,
    const float* __restrict__ b2,
    const float* __restrict__ w3,
    const float* __restrict__ b3,
    const float* __restrict__ wl,
    const float* __restrict__ bl,
    float* __restrict__ out) {
  __shared__ SMem sm;
  const int bid = blockIdx.x;
  if (bid & 1)
    gate_body(sm, bid >> 1, inp, w1, b1, w2, b2, w3, b3, out + OUT_IMG);
  else
    light_body(sm, bid >> 1, inp, wl, bl, out);
}

// ---------------------------------------------------------------------------
extern "C" void kernel_launch(void* const* d_in, const int* in_sizes, int n_in,
                              void* d_out, int out_size, void* d_ws, size_t ws_size,
                              hipStream_t stream) {
  const float* inp = (const float*)d_in[0];
  const float* w1  = (const float*)d_in[1];
  const float* b1  = (const float*)d_in[2];
  const float* w2  = (const float*)d_in[3];
  const float* b2  = (const float*)d_in[4];
  const float* w3  = (const float*)d_in[5];
  const float* b3  = (const float*)d_in[6];
  const float* wl  = (const float*)d_in[7];
  const float* bl  = (const float*)d_in[8];
  // d_in[9..14] = wc1,bc1,wc2,bc2,wc3,bc3: dead (gate sigmoid <= 1 -> mask always False)

  float* out = (float*)d_out;

  hipLaunchKernelGGL(fused_kernel, dim3(2*NBLK), dim3(256), 0, stream,
                     inp, w1, b1, w2, b2, w3, b3, wl, bl, out);
}

// Round 6
// 270.670 us; speedup vs baseline: 1.7170x; 1.7170x over previous
//
#include <hip/hip_runtime.h>
#include <math.h>

// Problem constants
#define CC 3
#define HH 1280
#define WW 720
#define BSZ 20
#define NHB 64
#define NWB 36
#define NBLK (NHB*NWB)          // 2304
#define OUT_IMG (3*5120*2880)   // 44236800

#define SLAB_PITCH 84           // 80 cols + pad; 84 % 32 = 20 -> row-bank offsets distinct for |drow|<8
#define SLAB_ROWS  60           // 3 c * 20 out-rows per slab

// Union'd LDS: light and gate are block-uniform branches of one kernel.
// This is the round-1 layout (measured 116us fused, VGPR 48, occ 45%).
union __align__(16) SMem {
  struct {
    float in_s[3][22][24];             // zero-padded input block, rows padded to 24
    float w_s[48*27 + 48];
    float slab[SLAB_ROWS][SLAB_PITCH]; // pixel-shuffled output slab (transpose buffer)
  } L;                                  // ~31.9 KB
  struct {
    float ins[3][26][28];              // clamped input patch (edge pad baked in)
    float w1s[16*27];
    float b1s[16];
    float w2s[8*16*9];
    float b2s[8];
    float w3s[200];
    float x1s[16][12][14];             // post-pool conv1 patch, cols padded to 14 (float2-aligned)
    float red[256];
    float b3s;
  } G;                                  // ~27.7 KB
};

__device__ __forceinline__ float fast_tanh(float x) {
  const float ax = fabsf(x);
  const float e = __expf(-2.0f * ax);
  const float t = (1.0f - e) / (1.0f + e);
  return x < 0.0f ? -t : t;
}

// ---------------------------------------------------------------------------
// Light expert (round-1 structure, verbatim): per 20x20 block, zero-pad
// conv3x3 (3->48) + pixel_shuffle(4) + clamp[0,0.6]+0.4. mask always False
// -> complex expert dead. Thread = one (oc,h) conv row, acc[20]; results
// staged through the LDS slab so global stores are float4-coalesced.
// NOTE (r2-r5 lesson): do NOT widen per-thread oc footprint here — every
// variant (acc[4][20], acc[4][10] templated, launch_bounds cap) lost to the
// register allocator (152 VGPR bloat or 380MB scratch spill). The compiler
// compiles this ~71-reg live set to 48 VGPR; that is the sweet spot.
// ---------------------------------------------------------------------------
__device__ __forceinline__ void light_body(
    SMem& sm, int l,
    const float* __restrict__ inp,
    const float* __restrict__ wl,
    const float* __restrict__ bl,
    float* __restrict__ out) {
  const int bi = l / NWB, bj = l % NWB;
  const int tid = threadIdx.x;
  float* w_s = sm.L.w_s;

  for (int i = tid; i < 3*22*24; i += 256) ((float*)sm.L.in_s)[i] = 0.0f;
  for (int i = tid; i < 48*27; i += 256) w_s[i] = wl[i];
  if (tid < 48) w_s[48*27 + tid] = bl[tid];
  __syncthreads();
  // stage 20x20x3 block; global float4 loads (WW=720 and 20*bj are mult of 4)
  for (int i = tid; i < 300; i += 256) {
    int x4 = i % 5; int r = (i / 5) % 20; int c = i / 100;
    const float4 v = *(const float4*)&inp[(c*HH + bi*BSZ + r)*WW + bj*BSZ + 4*x4];
    float* dst = &sm.L.in_s[c][r+1][1 + 4*x4];
    dst[0] = v.x; dst[1] = v.y; dst[2] = v.z; dst[3] = v.w;
  }
  __syncthreads();

  const int row0 = bi * 80, col0 = bj * 80;

  // 4 slabs of 5 conv-rows each: 48 oc * 5 h = 240 pairs per slab
  for (int slab = 0; slab < 4; ++slab) {
    if (tid < 240) {
      const int oc = tid % 48;
      const int hl = tid / 48;
      const int h  = slab*5 + hl;
      float wr[27];
      #pragma unroll
      for (int j = 0; j < 27; ++j) wr[j] = w_s[oc*27 + j];
      float acc[20];
      const float bias = w_s[48*27 + oc];
      #pragma unroll
      for (int w = 0; w < 20; ++w) acc[w] = bias;

      #pragma unroll
      for (int ic = 0; ic < 3; ++ic)
        #pragma unroll
        for (int ky = 0; ky < 3; ++ky) {
          const float* row = &sm.L.in_s[ic][h + ky][0];
          float r[24];
          #pragma unroll
          for (int j = 0; j < 6; ++j) {
            float4 v = ((const float4*)row)[j];   // ds_read_b128, near-broadcast across lanes
            r[j*4+0] = v.x; r[j*4+1] = v.y; r[j*4+2] = v.z; r[j*4+3] = v.w;
          }
          const float w0 = wr[ic*9 + ky*3 + 0];
          const float w1 = wr[ic*9 + ky*3 + 1];
          const float w2 = wr[ic*9 + ky*3 + 2];
          #pragma unroll
          for (int w = 0; w < 20; ++w)
            acc[w] += r[w]*w0 + r[w+1]*w1 + r[w+2]*w2;
        }

      // pixel_shuffle scatter -> LDS slab (ds_write_b32, <=2-way banks)
      // out[c][h*4+r1][w*4+r2] => slab[c*20 + hl*4 + r1][r2 + 4w]
      const int c  = oc >> 4;
      const int r1 = (oc >> 2) & 3;
      const int r2 = oc & 3;
      float* dst = &sm.L.slab[c*20 + hl*4 + r1][r2];
      #pragma unroll
      for (int w = 0; w < 20; ++w)
        dst[4*w] = fminf(fmaxf(acc[w], 0.0f), 0.6f) + 0.4f;
    }
    __syncthreads();

    // coalesced writeback: 60 rows x 20 float4 (320B contiguous per row segment)
    for (int i = tid; i < SLAB_ROWS*20; i += 256) {
      const int rrow = i / 20, cb = i % 20;
      const int c = rrow / 20, lr = rrow % 20;
      const float4 v = *(const float4*)&sm.L.slab[rrow][4*cb];
      const int gy = row0 + slab*20 + lr;
      *(float4*)&out[(c*5120 + gy)*2880 + col0 + 4*cb] = v;
    }
    __syncthreads();
  }
}

// ---------------------------------------------------------------------------
// Fused gate CNN (round-1 structure; + fast_tanh, + float2 stage-B reads):
//   stage A: conv1(3->16, edge-pad) + tanh + maxpool2 on a local 12x12 patch
//   stage B: conv2(16->8, edge-pad) + maxpool2 -> 8x5x5 window
//   stage C: 5x5x8 dot (conv3 stride 5) + sigmoid -> 1 scalar
// ---------------------------------------------------------------------------
__device__ __forceinline__ void gate_body(
    SMem& sm, int l,
    const float* __restrict__ inp,
    const float* __restrict__ w1,
    const float* __restrict__ b1,
    const float* __restrict__ w2,
    const float* __restrict__ b2,
    const float* __restrict__ w3,
    const float* __restrict__ b3,
    float* __restrict__ cv) {
  const int tid = threadIdx.x;
  const int oy = l / NWB, ox = l % NWB;

  for (int i = tid; i < 16*27; i += 256) sm.G.w1s[i] = w1[i];
  for (int i = tid; i < 8*16*9; i += 256) sm.G.w2s[i] = w2[i];
  for (int i = tid; i < 200; i += 256) sm.G.w3s[i] = w3[i];
  if (tid < 16) sm.G.b1s[tid] = b1[tid];
  if (tid < 8)  sm.G.b2s[tid] = b2[tid];
  if (tid == 0) sm.G.b3s = b3[0];

  // input patch rows [20*oy-3, 20*oy+23), cols [20*ox-3, 20*ox+23), clamped
  for (int i = tid; i < 3*26*28; i += 256) {
    int b = i % 28; int a = (i / 28) % 26; int ic = i / (26*28);
    int gy = 20*oy - 3 + a; gy = gy < 0 ? 0 : (gy > HH-1 ? HH-1 : gy);
    int gx = 20*ox - 3 + b; gx = gx < 0 ? 0 : (gx > WW-1 ? WW-1 : gx);
    sm.G.ins[ic][a][b] = inp[(ic*HH + gy)*WW + gx];
  }
  __syncthreads();

  // ---- stage A: one oc per thread-iteration (round-1 form, low VGPR)
  for (int v = tid; v < 16*12*12; v += 256) {
    int oc = v / 144; int rem = v - oc*144; int ly = rem / 12; int lx = rem - ly*12;
    int y1 = 10*oy - 1 + ly; y1 = y1 < 0 ? 0 : (y1 > 639 ? 639 : y1);
    int x1 = 10*ox - 1 + lx; x1 = x1 < 0 ? 0 : (x1 > 359 ? 359 : x1);
    int ry = 2*y1 + 2 - 20*oy;   // local row of conv input patch, in [0,22]
    int rx = 2*x1 + 2 - 20*ox;
    float patch[3][4][4];
    #pragma unroll
    for (int ic = 0; ic < 3; ++ic)
      #pragma unroll
      for (int d = 0; d < 4; ++d)
        #pragma unroll
        for (int e = 0; e < 4; ++e)
          patch[ic][d][e] = sm.G.ins[ic][ry + d][rx + e];
    float m = -1e30f;
    #pragma unroll
    for (int sy = 0; sy < 2; ++sy)
      #pragma unroll
      for (int sx = 0; sx < 2; ++sx) {
        float acc = sm.G.b1s[oc];
        #pragma unroll
        for (int ic = 0; ic < 3; ++ic)
          #pragma unroll
          for (int ky = 0; ky < 3; ++ky)
            #pragma unroll
            for (int kx = 0; kx < 3; ++kx)
              acc += patch[ic][sy+ky][sx+kx] * sm.G.w1s[(oc*3+ic)*9 + ky*3 + kx];
        m = fmaxf(m, acc);
      }
    // tanh monotonic: maxpool(tanh(.)) == tanh(maxpool(.))
    sm.G.x1s[oc][ly][lx] = fast_tanh(m);
  }
  __syncthreads();

  // ---- stage B (float2 reads: pitch-14 x1s, halves stage-B LDS instrs)
  float prod = 0.0f;
  if (tid < 200) {
    int oc2 = tid / 25; int rem = tid - oc2*25; int j = rem / 5; int i5 = rem - j*5;
    float a00 = sm.G.b2s[oc2], a01 = a00, a10 = a00, a11 = a00;
    for (int ic = 0; ic < 16; ++ic) {
      float p[4][4];
      #pragma unroll
      for (int d = 0; d < 4; ++d) {
        const float2 pa = *(const float2*)&sm.G.x1s[ic][2*j + d][2*i5];
        const float2 pb = *(const float2*)&sm.G.x1s[ic][2*j + d][2*i5 + 2];
        p[d][0] = pa.x; p[d][1] = pa.y; p[d][2] = pb.x; p[d][3] = pb.y;
      }
      #pragma unroll
      for (int ky = 0; ky < 3; ++ky)
        #pragma unroll
        for (int kx = 0; kx < 3; ++kx) {
          float wv = sm.G.w2s[((oc2*16 + ic)*3 + ky)*3 + kx];
          a00 += p[ky  ][kx  ]*wv;
          a01 += p[ky  ][kx+1]*wv;
          a10 += p[ky+1][kx  ]*wv;
          a11 += p[ky+1][kx+1]*wv;
        }
    }
    float x2 = fmaxf(fmaxf(a00, a01), fmaxf(a10, a11));
    prod = x2 * sm.G.w3s[tid];          // w3 index (oc2*5+j)*5+i5 == tid
  }
  sm.G.red[tid] = prod;
  __syncthreads();

  // ---- stage C
  if (tid < 64) {
    float s = sm.G.red[tid] + sm.G.red[tid+64] + sm.G.red[tid+128] + sm.G.red[tid+192];
    #pragma unroll
    for (int off = 32; off > 0; off >>= 1) s += __shfl_down(s, off);
    if (tid == 0)
      cv[l] = 1.0f / (1.0f + expf(-(s + sm.G.b3s)));
  }
}

// ---------------------------------------------------------------------------
// One launch, interleaved light/gate blocks (block-uniform branch).
// Plain __launch_bounds__(256): round-1's allocator regime (48 VGPR, 45% occ).
// ---------------------------------------------------------------------------
__global__ __launch_bounds__(256) void fused_kernel(
    const float* __restrict__ inp,
    const float* __restrict__ w1,
    const float* __restrict__ b1,
    const float* __restrict__ w2,
    const float* __restrict__ b2,
    const float* __restrict__ w3,
    const float* __restrict__ b3,
    const float* __restrict__ wl,
    const float* __restrict__ bl,
    float* __restrict__ out) {
  __shared__ SMem sm;
  const int bid = blockIdx.x;
  if (bid & 1)
    gate_body(sm, bid >> 1, inp, w1, b1, w2, b2, w3, b3, out + OUT_IMG);
  else
    light_body(sm, bid >> 1, inp, wl, bl, out);
}

// ---------------------------------------------------------------------------
extern "C" void kernel_launch(void* const* d_in, const int* in_sizes, int n_in,
                              void* d_out, int out_size, void* d_ws, size_t ws_size,
                              hipStream_t stream) {
  const float* inp = (const float*)d_in[0];
  const float* w1  = (const float*)d_in[1];
  const float* b1  = (const float*)d_in[2];
  const float* w2  = (const float*)d_in[3];
  const float* b2  = (const float*)d_in[4];
  const float* w3  = (const float*)d_in[5];
  const float* b3  = (const float*)d_in[6];
  const float* wl  = (const float*)d_in[7];
  const float* bl  = (const float*)d_in[8];
  // d_in[9..14] = wc1,bc1,wc2,bc2,wc3,bc3: dead (gate sigmoid <= 1 -> mask always False)

  float* out = (float*)d_out;

  hipLaunchKernelGGL(fused_kernel, dim3(2*NBLK), dim3(256), 0, stream,
                     inp, w1, b1, w2, b2, w3, b3, wl, bl, out);
}

// Round 7
// 262.100 us; speedup vs baseline: 1.7732x; 1.0327x over previous
//
#include <hip/hip_runtime.h>
#include <math.h>

// Problem constants
#define CC 3
#define HH 1280
#define WW 720
#define BSZ 20
#define NHB 64
#define NWB 36
#define NBLK (NHB*NWB)          // 2304
#define OUT_IMG (3*5120*2880)   // 44236800

#define SLAB_PITCH 84           // 80 cols + pad; 84 % 32 = 20 -> row-bank offsets distinct
#define SLAB_ROWS  60           // 3 c * 20 out-rows per slab

// Union'd LDS: light and gate are block-uniform branches of one kernel.
union __align__(16) SMem {
  struct {
    float in_s[3][22][24];             // zero-padded input block, rows padded to 24
    float w_s[48*27 + 48];
    float slab[SLAB_ROWS][SLAB_PITCH]; // pixel-shuffled output slab (transpose buffer)
  } L;                                  // ~31.9 KB  (union max - unchanged)
  struct {
    float ins[3][26][28];              // clamped input patch (edge pad baked in)
    float w1t[27][16];                 // transposed conv1 weights [k][oc] (float4 per 4-oc)
    float b1s[16];
    float w2t[16][9][8];               // transposed conv2 weights [ic][k][oc2]
    float b2s[8];
    float w3s[200];
    float x1s[16][12][14];             // post-pool conv1 patch, cols padded to 14 (float2)
    float red[256];
    float b3s;
  } G;                                  // ~27.7 KB
};

__device__ __forceinline__ float fast_tanh(float x) {
  const float ax = fabsf(x);
  const float e = __expf(-2.0f * ax);
  const float t = (1.0f - e) / (1.0f + e);
  return x < 0.0f ? -t : t;
}

// ---------------------------------------------------------------------------
// Light expert (round-1 structure, UNTOUCHED - measured 116us/48 VGPR):
// per 20x20 block, zero-pad conv3x3 (3->48) + pixel_shuffle(4) +
// clamp[0,0.6]+0.4; slab-staged coalesced stores.
// r2-r5 lesson: do NOT widen per-thread oc footprint here.
// ---------------------------------------------------------------------------
__device__ __forceinline__ void light_body(
    SMem& sm, int l,
    const float* __restrict__ inp,
    const float* __restrict__ wl,
    const float* __restrict__ bl,
    float* __restrict__ out) {
  const int bi = l / NWB, bj = l % NWB;
  const int tid = threadIdx.x;
  float* w_s = sm.L.w_s;

  for (int i = tid; i < 3*22*24; i += 256) ((float*)sm.L.in_s)[i] = 0.0f;
  for (int i = tid; i < 48*27; i += 256) w_s[i] = wl[i];
  if (tid < 48) w_s[48*27 + tid] = bl[tid];
  __syncthreads();
  // stage 20x20x3 block; global float4 loads (WW=720 and 20*bj are mult of 4)
  for (int i = tid; i < 300; i += 256) {
    int x4 = i % 5; int r = (i / 5) % 20; int c = i / 100;
    const float4 v = *(const float4*)&inp[(c*HH + bi*BSZ + r)*WW + bj*BSZ + 4*x4];
    float* dst = &sm.L.in_s[c][r+1][1 + 4*x4];
    dst[0] = v.x; dst[1] = v.y; dst[2] = v.z; dst[3] = v.w;
  }
  __syncthreads();

  const int row0 = bi * 80, col0 = bj * 80;

  // 4 slabs of 5 conv-rows each: 48 oc * 5 h = 240 pairs per slab
  for (int slab = 0; slab < 4; ++slab) {
    if (tid < 240) {
      const int oc = tid % 48;
      const int hl = tid / 48;
      const int h  = slab*5 + hl;
      float wr[27];
      #pragma unroll
      for (int j = 0; j < 27; ++j) wr[j] = w_s[oc*27 + j];
      float acc[20];
      const float bias = w_s[48*27 + oc];
      #pragma unroll
      for (int w = 0; w < 20; ++w) acc[w] = bias;

      #pragma unroll
      for (int ic = 0; ic < 3; ++ic)
        #pragma unroll
        for (int ky = 0; ky < 3; ++ky) {
          const float* row = &sm.L.in_s[ic][h + ky][0];
          float r[24];
          #pragma unroll
          for (int j = 0; j < 6; ++j) {
            float4 v = ((const float4*)row)[j];   // ds_read_b128
            r[j*4+0] = v.x; r[j*4+1] = v.y; r[j*4+2] = v.z; r[j*4+3] = v.w;
          }
          const float w0 = wr[ic*9 + ky*3 + 0];
          const float w1 = wr[ic*9 + ky*3 + 1];
          const float w2 = wr[ic*9 + ky*3 + 2];
          #pragma unroll
          for (int w = 0; w < 20; ++w)
            acc[w] += r[w]*w0 + r[w+1]*w1 + r[w+2]*w2;
        }

      // pixel_shuffle scatter -> LDS slab (ds_write_b32, <=2-way banks)
      const int c  = oc >> 4;
      const int r1 = (oc >> 2) & 3;
      const int r2 = oc & 3;
      float* dst = &sm.L.slab[c*20 + hl*4 + r1][r2];
      #pragma unroll
      for (int w = 0; w < 20; ++w)
        dst[4*w] = fminf(fmaxf(acc[w], 0.0f), 0.6f) + 0.4f;
    }
    __syncthreads();

    // coalesced writeback: 60 rows x 20 float4
    for (int i = tid; i < SLAB_ROWS*20; i += 256) {
      const int rrow = i / 20, cb = i % 20;
      const int c = rrow / 20, lr = rrow % 20;
      const float4 v = *(const float4*)&sm.L.slab[rrow][4*cb];
      const int gy = row0 + slab*20 + lr;
      *(float4*)&out[(c*5120 + gy)*2880 + col0 + 4*cb] = v;
    }
    __syncthreads();
  }
}

// ---------------------------------------------------------------------------
// Fused gate CNN - LDS-traffic version:
//   stage A: 4 oc per patch load (patch LDS reads /4, float2 reads, float4 w)
//   stage B: 4 oc2 per window (window LDS reads /4, float4 broadcast weights)
//   stage C: reduce 200 products + sigmoid
// ---------------------------------------------------------------------------
__device__ __forceinline__ void gate_body(
    SMem& sm, int l,
    const float* __restrict__ inp,
    const float* __restrict__ w1,
    const float* __restrict__ b1,
    const float* __restrict__ w2,
    const float* __restrict__ b2,
    const float* __restrict__ w3,
    const float* __restrict__ b3,
    float* __restrict__ cv) {
  const int tid = threadIdx.x;
  const int oy = l / NWB, ox = l % NWB;

  // transposed conv1 weights: w1t[k][oc] = w1[oc*27 + k]
  for (int i = tid; i < 27*16; i += 256) {
    int k = i >> 4, oc = i & 15;
    sm.G.w1t[k][oc] = w1[oc*27 + k];
  }
  // transposed conv2 weights: w2t[ic][k][oc2] = w2[(oc2*16+ic)*9 + k]
  for (int i = tid; i < 16*9*8; i += 256) {
    int ic = i / 72; int rem = i - ic*72; int k = rem >> 3; int oc2 = rem & 7;
    ((float*)sm.G.w2t)[i] = w2[(oc2*16 + ic)*9 + k];
  }
  for (int i = tid; i < 200; i += 256) sm.G.w3s[i] = w3[i];
  if (tid < 16) sm.G.b1s[tid] = b1[tid];
  if (tid < 8)  sm.G.b2s[tid] = b2[tid];
  if (tid == 0) sm.G.b3s = b3[0];

  // input patch rows [20*oy-3, 20*oy+23), cols [20*ox-3, 20*ox+23), clamped
  for (int i = tid; i < 3*26*28; i += 256) {
    int b = i % 28; int a = (i / 28) % 26; int ic = i / (26*28);
    int gy = 20*oy - 3 + a; gy = gy < 0 ? 0 : (gy > HH-1 ? HH-1 : gy);
    int gx = 20*ox - 3 + b; gx = gx < 0 ? 0 : (gx > WW-1 ? WW-1 : gx);
    sm.G.ins[ic][a][b] = inp[(ic*HH + gy)*WW + gx];
  }
  __syncthreads();

  // ---- stage A: 4 oc per thread-iteration, patch loaded once per 4 oc
  for (int idx = tid; idx < 4*144; idx += 256) {
    const int ocq = idx / 144;                 // 0..3 -> oc = 4*ocq + q
    const int pos = idx - ocq*144;
    const int ly = pos / 12, lx = pos - ly*12;
    int y1 = 10*oy - 1 + ly; y1 = y1 < 0 ? 0 : (y1 > 639 ? 639 : y1);
    int x1 = 10*ox - 1 + lx; x1 = x1 < 0 ? 0 : (x1 > 359 ? 359 : x1);
    const int ry = 2*y1 + 2 - 20*oy;           // even, in [0,22]
    const int rx = 2*x1 + 2 - 20*ox;           // even, in [0,24]

    float patch[3][4][4];
    #pragma unroll
    for (int ic = 0; ic < 3; ++ic)
      #pragma unroll
      for (int d = 0; d < 4; ++d) {
        const float2 pa = *(const float2*)&sm.G.ins[ic][ry + d][rx];
        const float2 pb = *(const float2*)&sm.G.ins[ic][ry + d][rx + 2];
        patch[ic][d][0] = pa.x; patch[ic][d][1] = pa.y;
        patch[ic][d][2] = pb.x; patch[ic][d][3] = pb.y;
      }

    const float4 b4 = *(const float4*)&sm.G.b1s[4*ocq];
    float a00[4], a01[4], a10[4], a11[4];
    a00[0]=b4.x; a00[1]=b4.y; a00[2]=b4.z; a00[3]=b4.w;
    a01[0]=b4.x; a01[1]=b4.y; a01[2]=b4.z; a01[3]=b4.w;
    a10[0]=b4.x; a10[1]=b4.y; a10[2]=b4.z; a10[3]=b4.w;
    a11[0]=b4.x; a11[1]=b4.y; a11[2]=b4.z; a11[3]=b4.w;

    #pragma unroll
    for (int ic = 0; ic < 3; ++ic)
      #pragma unroll
      for (int ky = 0; ky < 3; ++ky)
        #pragma unroll
        for (int kx = 0; kx < 3; ++kx) {
          const int k = (ic*3 + ky)*3 + kx;
          const float4 wv = *(const float4*)&sm.G.w1t[k][4*ocq];
          const float p00 = patch[ic][ky  ][kx  ];
          const float p01 = patch[ic][ky  ][kx+1];
          const float p10 = patch[ic][ky+1][kx  ];
          const float p11 = patch[ic][ky+1][kx+1];
          a00[0] += p00*wv.x; a00[1] += p00*wv.y; a00[2] += p00*wv.z; a00[3] += p00*wv.w;
          a01[0] += p01*wv.x; a01[1] += p01*wv.y; a01[2] += p01*wv.z; a01[3] += p01*wv.w;
          a10[0] += p10*wv.x; a10[1] += p10*wv.y; a10[2] += p10*wv.z; a10[3] += p10*wv.w;
          a11[0] += p11*wv.x; a11[1] += p11*wv.y; a11[2] += p11*wv.z; a11[3] += p11*wv.w;
        }

    #pragma unroll
    for (int q = 0; q < 4; ++q) {
      const float m = fmaxf(fmaxf(a00[q], a01[q]), fmaxf(a10[q], a11[q]));
      // tanh monotonic: maxpool(tanh(.)) == tanh(maxpool(.))
      sm.G.x1s[4*ocq + q][ly][lx] = fast_tanh(m);
    }
  }
  __syncthreads();

  // ---- stage B: 4 oc2 per thread; x1s window read once per oc2-quad.
  // thread t<50: q = t/25 (oc2 = 4q+qq), win = t%25 -> (j,i5)
  sm.G.red[tid] = 0.0f;
  __syncthreads();
  if (tid < 50) {
    const int q   = tid / 25;
    const int win = tid - q*25;
    const int j = win / 5, i5 = win - j*5;

    const float4 b4 = *(const float4*)&sm.G.b2s[4*q];
    float a00[4], a01[4], a10[4], a11[4];
    a00[0]=b4.x; a00[1]=b4.y; a00[2]=b4.z; a00[3]=b4.w;
    a01[0]=b4.x; a01[1]=b4.y; a01[2]=b4.z; a01[3]=b4.w;
    a10[0]=b4.x; a10[1]=b4.y; a10[2]=b4.z; a10[3]=b4.w;
    a11[0]=b4.x; a11[1]=b4.y; a11[2]=b4.z; a11[3]=b4.w;

    for (int ic = 0; ic < 16; ++ic) {
      float p[4][4];
      #pragma unroll
      for (int d = 0; d < 4; ++d) {
        const float2 pa = *(const float2*)&sm.G.x1s[ic][2*j + d][2*i5];
        const float2 pb = *(const float2*)&sm.G.x1s[ic][2*j + d][2*i5 + 2];
        p[d][0] = pa.x; p[d][1] = pa.y; p[d][2] = pb.x; p[d][3] = pb.y;
      }
      #pragma unroll
      for (int ky = 0; ky < 3; ++ky)
        #pragma unroll
        for (int kx = 0; kx < 3; ++kx) {
          const float4 wv = *(const float4*)&sm.G.w2t[ic][ky*3 + kx][4*q];
          const float p00 = p[ky  ][kx  ];
          const float p01 = p[ky  ][kx+1];
          const float p10 = p[ky+1][kx  ];
          const float p11 = p[ky+1][kx+1];
          a00[0] += p00*wv.x; a00[1] += p00*wv.y; a00[2] += p00*wv.z; a00[3] += p00*wv.w;
          a01[0] += p01*wv.x; a01[1] += p01*wv.y; a01[2] += p01*wv.z; a01[3] += p01*wv.w;
          a10[0] += p10*wv.x; a10[1] += p10*wv.y; a10[2] += p10*wv.z; a10[3] += p10*wv.w;
          a11[0] += p11*wv.x; a11[1] += p11*wv.y; a11[2] += p11*wv.z; a11[3] += p11*wv.w;
        }
    }
    #pragma unroll
    for (int qq = 0; qq < 4; ++qq) {
      const float x2 = fmaxf(fmaxf(a00[qq], a01[qq]), fmaxf(a10[qq], a11[qq]));
      const int oc2 = 4*q + qq;
      sm.G.red[oc2*25 + win] = x2 * sm.G.w3s[oc2*25 + win];
    }
  }
  __syncthreads();

  // ---- stage C
  if (tid < 64) {
    float s = sm.G.red[tid] + sm.G.red[tid+64] + sm.G.red[tid+128] + sm.G.red[tid+192];
    #pragma unroll
    for (int off = 32; off > 0; off >>= 1) s += __shfl_down(s, off);
    if (tid == 0)
      cv[l] = 1.0f / (1.0f + expf(-(s + sm.G.b3s)));
  }
}

// ---------------------------------------------------------------------------
// One launch, interleaved light/gate blocks (block-uniform branch).
// Plain __launch_bounds__(256); occupancy is LDS-capped at 4 blocks/CU,
// so gate-side VGPR up to 128 is free.
// ---------------------------------------------------------------------------
__global__ __launch_bounds__(256) void fused_kernel(
    const float* __restrict__ inp,
    const float* __restrict__ w1,
    const float* __restrict__ b1,
    const float* __restrict__ w2,
    const float* __restrict__ b2,
    const float* __restrict__ w3,
    const float* __restrict__ b3,
    const float* __restrict__ wl,
    const float* __restrict__ bl,
    float* __restrict__ out) {
  __shared__ SMem sm;
  const int bid = blockIdx.x;
  if (bid & 1)
    gate_body(sm, bid >> 1, inp, w1, b1, w2, b2, w3, b3, out + OUT_IMG);
  else
    light_body(sm, bid >> 1, inp, wl, bl, out);
}

// ---------------------------------------------------------------------------
extern "C" void kernel_launch(void* const* d_in, const int* in_sizes, int n_in,
                              void* d_out, int out_size, void* d_ws, size_t ws_size,
                              hipStream_t stream) {
  const float* inp = (const float*)d_in[0];
  const float* w1  = (const float*)d_in[1];
  const float* b1  = (const float*)d_in[2];
  const float* w2  = (const float*)d_in[3];
  const float* b2  = (const float*)d_in[4];
  const float* w3  = (const float*)d_in[5];
  const float* b3  = (const float*)d_in[6];
  const float* wl  = (const float*)d_in[7];
  const float* bl  = (const float*)d_in[8];
  // d_in[9..14] = wc1,bc1,wc2,bc2,wc3,bc3: dead (gate sigmoid <= 1 -> mask always False)

  float* out = (float*)d_out;

  hipLaunchKernelGGL(fused_kernel, dim3(2*NBLK), dim3(256), 0, stream,
                     inp, w1, b1, w2, b2, w3, b3, wl, bl, out);
}